// Round 1
// baseline (250.830 us; speedup 1.0000x reference)
//
#include <hip/hip_runtime.h>
#include <math.h>

// Sizes (fixed for this problem)
#define B    256
#define T    512
#define CTX  512
#define MEL  160
#define PRE  128
#define ATT  256
#define RNN  768
#define G3   2304   // 3*RNN

// ---------------------------------------------------------------------------
// PreNet: relu(xf @ w1.T + b1) -> relu(h @ w2.T + b2)
// grid: B blocks, 128 threads
// ---------------------------------------------------------------------------
__global__ void prenet_kernel(const float* __restrict__ x,
                              const float* __restrict__ w1, const float* __restrict__ b1,
                              const float* __restrict__ w2, const float* __restrict__ b2,
                              float* __restrict__ h_pre) {
    __shared__ float xf[MEL];
    __shared__ float h1[PRE];
    const int b = blockIdx.x, tid = threadIdx.x;
    for (int i = tid; i < MEL; i += 128) xf[i] = x[b * MEL + i];
    __syncthreads();
    float acc = b1[tid];
    const float* wr = w1 + (size_t)tid * MEL;
    #pragma unroll 4
    for (int k = 0; k < MEL; ++k) acc += xf[k] * wr[k];
    h1[tid] = fmaxf(acc, 0.f);
    __syncthreads();
    float acc2 = b2[tid];
    const float* wr2 = w2 + (size_t)tid * PRE;
    #pragma unroll 4
    for (int k = 0; k < PRE; ++k) acc2 += h1[k] * wr2[k];
    h_pre[b * PRE + tid] = fmaxf(acc2, 0.f);
}

// ---------------------------------------------------------------------------
// Attention GRUCell: h_pre (B,128) x h_att (B,256) -> h_att_new (B,256)
// grid: 64 blocks (4 batches each), 256 threads (one output feature each)
// Writes h_att_new to d_out slice AND into x_dec[:, 0:256]
// ---------------------------------------------------------------------------
__global__ void attgru_kernel(const float* __restrict__ h_pre, const float* __restrict__ h_att,
                              const float* __restrict__ wi, const float* __restrict__ wh,
                              const float* __restrict__ bi, const float* __restrict__ bh,
                              float* __restrict__ h_att_out, float* __restrict__ x_dec) {
    __shared__ float hp[4][PRE];
    __shared__ float ha[4][ATT];
    const int tid = threadIdx.x;
    const int b0 = blockIdx.x * 4;
    for (int i = tid; i < 4 * PRE; i += 256) hp[i / PRE][i % PRE] = h_pre[b0 * PRE + i];
    for (int i = tid; i < 4 * ATT; i += 256) ha[i / ATT][i % ATT] = h_att[b0 * ATT + i];
    __syncthreads();
    const int j = tid;  // output feature 0..255
    float gr[4], gz[4], gn[4], hr[4], hz[4], hn[4];
    {
        const float bir = bi[j], biz = bi[ATT + j], bin = bi[2 * ATT + j];
        const float bhr = bh[j], bhz = bh[ATT + j], bhn = bh[2 * ATT + j];
        for (int q = 0; q < 4; ++q) { gr[q] = bir; gz[q] = biz; gn[q] = bin; hr[q] = bhr; hz[q] = bhz; hn[q] = bhn; }
    }
    const float* wir = wi + (size_t)j * PRE;
    const float* wiz = wi + (size_t)(ATT + j) * PRE;
    const float* win = wi + (size_t)(2 * ATT + j) * PRE;
    for (int k = 0; k < PRE; ++k) {
        const float a = wir[k], c = wiz[k], d = win[k];
        #pragma unroll
        for (int q = 0; q < 4; ++q) { const float h_ = hp[q][k]; gr[q] += a * h_; gz[q] += c * h_; gn[q] += d * h_; }
    }
    const float* whr = wh + (size_t)j * ATT;
    const float* whz = wh + (size_t)(ATT + j) * ATT;
    const float* whn = wh + (size_t)(2 * ATT + j) * ATT;
    for (int k = 0; k < ATT; ++k) {
        const float a = whr[k], c = whz[k], d = whn[k];
        #pragma unroll
        for (int q = 0; q < 4; ++q) { const float h_ = ha[q][k]; hr[q] += a * h_; hz[q] += c * h_; hn[q] += d * h_; }
    }
    #pragma unroll
    for (int q = 0; q < 4; ++q) {
        const float r = 1.f / (1.f + expf(-(gr[q] + hr[q])));
        const float z = 1.f / (1.f + expf(-(gz[q] + hz[q])));
        const float n = tanhf(gn[q] + r * hn[q]);
        const float hnew = (1.f - z) * n + z * ha[q][j];
        h_att_out[(size_t)(b0 + q) * ATT + j] = hnew;
        x_dec[(size_t)(b0 + q) * RNN + j] = hnew;
    }
}

// ---------------------------------------------------------------------------
// q = h_att_new @ q_w.T + q_b : (B, 512)
// grid: 64 blocks (4 batches each), 512 threads (one column each)
// ---------------------------------------------------------------------------
__global__ void qproj_kernel(const float* __restrict__ h_att_new,
                             const float* __restrict__ qw, const float* __restrict__ qb,
                             float* __restrict__ q) {
    __shared__ float ha[4][ATT];
    const int tid = threadIdx.x;
    const int b0 = blockIdx.x * 4;
    for (int i = tid; i < 4 * ATT; i += 512) ha[i / ATT][i % ATT] = h_att_new[b0 * ATT + i];
    __syncthreads();
    const int c = tid;
    float acc[4];
    const float bb = qb[c];
    for (int qq = 0; qq < 4; ++qq) acc[qq] = bb;
    const float* wr = qw + (size_t)c * ATT;
    for (int k = 0; k < ATT; ++k) {
        const float wv = wr[k];
        #pragma unroll
        for (int qq = 0; qq < 4; ++qq) acc[qq] += wv * ha[qq][k];
    }
    for (int qq = 0; qq < 4; ++qq) q[(size_t)(b0 + qq) * CTX + c] = acc[qq];
}

// ---------------------------------------------------------------------------
// Fused memory pass: one read of memory (B,T,CTX) producing
//   e[b,t]  = dot(memory[b,t,:], q[b,:]) / sqrt(CTX)
//   ctx_partial[slice][b][c] = sum_{t in slice} w[b,t] * memory[b,t,c]
// grid: dim3(8, B), 256 threads (4 waves x 16 t-rows each)
// ---------------------------------------------------------------------------
__global__ void mempass_kernel(const float* __restrict__ mem, const float* __restrict__ w,
                               const float* __restrict__ q, float* __restrict__ e,
                               float* __restrict__ ctx_part) {
    const int b = blockIdx.y, slice = blockIdx.x;
    const int tid = threadIdx.x;
    const int wave = tid >> 6, lane = tid & 63;
    __shared__ float qs[CTX];
    __shared__ float ctx_s[4][CTX];
    for (int i = tid; i < CTX; i += 256) qs[i] = q[(size_t)b * CTX + i];
    __syncthreads();

    const int c0 = lane * 4;
    const int c1 = 256 + lane * 4;
    // hoist q fragments to registers
    const float q0 = qs[c0], q1 = qs[c0 + 1], q2 = qs[c0 + 2], q3 = qs[c0 + 3];
    const float q4 = qs[c1], q5 = qs[c1 + 1], q6 = qs[c1 + 2], q7 = qs[c1 + 3];

    const float* mb = mem + (size_t)b * T * CTX;
    float acc[8] = {0.f, 0.f, 0.f, 0.f, 0.f, 0.f, 0.f, 0.f};
    const float invs = 0.04419417382415922f;  // 1/sqrt(512)
    const int t0 = slice * 64 + wave * 16;

    for (int i = 0; i < 16; ++i) {
        const int t = t0 + i;
        const float* row = mb + (size_t)t * CTX;
        const float4 m0 = *(const float4*)(row + c0);
        const float4 m1 = *(const float4*)(row + c1);
        const float wt = w[(size_t)b * T + t];
        float ep = m0.x * q0 + m0.y * q1 + m0.z * q2 + m0.w * q3
                 + m1.x * q4 + m1.y * q5 + m1.z * q6 + m1.w * q7;
        #pragma unroll
        for (int off = 32; off; off >>= 1) ep += __shfl_xor(ep, off);
        if (lane == 0) e[(size_t)b * T + t] = ep * invs;
        acc[0] += wt * m0.x; acc[1] += wt * m0.y; acc[2] += wt * m0.z; acc[3] += wt * m0.w;
        acc[4] += wt * m1.x; acc[5] += wt * m1.y; acc[6] += wt * m1.z; acc[7] += wt * m1.w;
    }
    ctx_s[wave][c0] = acc[0]; ctx_s[wave][c0 + 1] = acc[1]; ctx_s[wave][c0 + 2] = acc[2]; ctx_s[wave][c0 + 3] = acc[3];
    ctx_s[wave][c1] = acc[4]; ctx_s[wave][c1 + 1] = acc[5]; ctx_s[wave][c1 + 2] = acc[6]; ctx_s[wave][c1 + 3] = acc[7];
    __syncthreads();
    for (int c = tid; c < CTX; c += 256) {
        const float s = ctx_s[0][c] + ctx_s[1][c] + ctx_s[2][c] + ctx_s[3][c];
        ctx_part[((size_t)slice * B + b) * CTX + c] = s;
    }
}

// ---------------------------------------------------------------------------
// Reduce 8 ctx partial slices -> x_dec[:, 256:768]
// grid: 512 blocks, 256 threads (one (b,c) each)
// ---------------------------------------------------------------------------
__global__ void ctx_reduce_kernel(const float* __restrict__ part, float* __restrict__ x_dec) {
    const int idx = blockIdx.x * 256 + threadIdx.x;  // 131072 total
    const int b = idx >> 9, c = idx & 511;
    float s = 0.f;
    #pragma unroll
    for (int sl = 0; sl < 8; ++sl) s += part[((size_t)sl * B + b) * CTX + c];
    x_dec[(size_t)b * RNN + ATT + c] = s;
}

// ---------------------------------------------------------------------------
// Softmax over e, times Markov prior, renormalized -> w_new
// grid: B blocks, 256 threads (2 t's each)
// ---------------------------------------------------------------------------
__global__ void softmax_prior_kernel(const float* __restrict__ e, const float* __restrict__ w,
                                     float* __restrict__ w_new) {
    const int b = blockIdx.x, tid = threadIdx.x;
    const int lane = tid & 63, wv = tid >> 6;
    __shared__ float red[4];
    const float* eb = e + (size_t)b * T;
    const float* wb = w + (size_t)b * T;
    const float e0 = eb[tid], e1 = eb[tid + 256];

    float m = fmaxf(e0, e1);
    #pragma unroll
    for (int o = 32; o; o >>= 1) m = fmaxf(m, __shfl_xor(m, o));
    if (lane == 0) red[wv] = m;
    __syncthreads();
    m = fmaxf(fmaxf(red[0], red[1]), fmaxf(red[2], red[3]));
    __syncthreads();

    const float x0 = expf(e0 - m), x1 = expf(e1 - m);
    float s = x0 + x1;
    #pragma unroll
    for (int o = 32; o; o >>= 1) s += __shfl_xor(s, o);
    if (lane == 0) red[wv] = s;
    __syncthreads();
    s = red[0] + red[1] + red[2] + red[3];
    __syncthreads();

    const float p0 = 0.5f * (wb[tid] + (tid > 0 ? wb[tid - 1] : 0.f));
    const float p1 = 0.5f * (wb[tid + 256] + wb[tid + 255]);
    const float m0 = (x0 / s) * p0;
    const float m1 = (x1 / s) * p1;
    float s2 = m0 + m1;
    #pragma unroll
    for (int o = 32; o; o >>= 1) s2 += __shfl_xor(s2, o);
    if (lane == 0) red[wv] = s2;
    __syncthreads();
    s2 = red[0] + red[1] + red[2] + red[3];
    const float inv = 1.f / (s2 + 1e-8f);
    w_new[(size_t)b * T + tid] = m0 * inv;
    w_new[(size_t)b * T + tid + 256] = m1 * inv;
}

// ---------------------------------------------------------------------------
// fp32 GEMM with bias: C[M=256, N=2304] = A[256,768] @ W[2304,768]^T + bias
// blockIdx.z selects (A0,W0,b0,C0) = gi  or  (A1,W1,b1,C1) = gh
// 64x64 tile, BK=32, 256 threads, 4x4 micro-tile
// ---------------------------------------------------------------------------
#define BM 64
#define BN 64
#define BK 32
__global__ __launch_bounds__(256) void gemm_bias_kernel(
        const float* __restrict__ A0, const float* __restrict__ A1,
        const float* __restrict__ W0, const float* __restrict__ W1,
        const float* __restrict__ bias0, const float* __restrict__ bias1,
        float* __restrict__ C0, float* __restrict__ C1) {
    const float* A = blockIdx.z ? A1 : A0;
    const float* W = blockIdx.z ? W1 : W0;
    const float* bias = blockIdx.z ? bias1 : bias0;
    float* C = blockIdx.z ? C1 : C0;

    const int m0 = blockIdx.y * BM, n0 = blockIdx.x * BN;
    __shared__ float As[BK][BM + 4];
    __shared__ float Ws[BK][BN + 4];
    const int tid = threadIdx.x;
    const int tx = tid & 15, ty = tid >> 4;

    float acc[4][4] = {};
    for (int k0 = 0; k0 < RNN; k0 += BK) {
        #pragma unroll
        for (int f = tid; f < 512; f += 256) {
            const int row = f >> 3, c4 = (f & 7) * 4;
            const float4 v = *(const float4*)(A + (size_t)(m0 + row) * RNN + k0 + c4);
            As[c4 + 0][row] = v.x; As[c4 + 1][row] = v.y; As[c4 + 2][row] = v.z; As[c4 + 3][row] = v.w;
        }
        #pragma unroll
        for (int f = tid; f < 512; f += 256) {
            const int row = f >> 3, c4 = (f & 7) * 4;
            const float4 v = *(const float4*)(W + (size_t)(n0 + row) * RNN + k0 + c4);
            Ws[c4 + 0][row] = v.x; Ws[c4 + 1][row] = v.y; Ws[c4 + 2][row] = v.z; Ws[c4 + 3][row] = v.w;
        }
        __syncthreads();
        #pragma unroll
        for (int kk = 0; kk < BK; ++kk) {
            const float4 a4 = *(const float4*)&As[kk][ty * 4];
            const float4 w4 = *(const float4*)&Ws[kk][tx * 4];
            const float a[4] = {a4.x, a4.y, a4.z, a4.w};
            const float wv[4] = {w4.x, w4.y, w4.z, w4.w};
            #pragma unroll
            for (int i = 0; i < 4; ++i)
                #pragma unroll
                for (int j = 0; j < 4; ++j) acc[i][j] += a[i] * wv[j];
        }
        __syncthreads();
    }
    #pragma unroll
    for (int i = 0; i < 4; ++i) {
        const int row = m0 + ty * 4 + i;
        #pragma unroll
        for (int j = 0; j < 4; ++j) {
            const int col = n0 + tx * 4 + j;
            C[(size_t)row * G3 + col] = acc[i][j] + bias[col];
        }
    }
}

// ---------------------------------------------------------------------------
// GRU epilogue + residual: out = gru(x_in, h_prev; gi, gh) + x_in
// grid: 768 blocks, 256 threads (one element each)
// ---------------------------------------------------------------------------
__global__ void gru_res_kernel(const float* __restrict__ x_in, const float* __restrict__ h_prev,
                               const float* __restrict__ gi, const float* __restrict__ gh,
                               float* __restrict__ out0, float* __restrict__ out1) {
    const int idx = blockIdx.x * 256 + threadIdx.x;  // 196608 total
    const int b = idx / RNN, j = idx % RNN;
    const float* gib = gi + (size_t)b * G3;
    const float* ghb = gh + (size_t)b * G3;
    const float ir = gib[j], iz = gib[RNN + j], in_ = gib[2 * RNN + j];
    const float hr = ghb[j], hz = ghb[RNN + j], hn = ghb[2 * RNN + j];
    const float r = 1.f / (1.f + expf(-(ir + hr)));
    const float z = 1.f / (1.f + expf(-(iz + hz)));
    const float n = tanhf(in_ + r * hn);
    const float h = (1.f - z) * n + z * h_prev[idx];
    const float res = h + x_in[idx];
    out0[idx] = res;
    if (out1) out1[idx] = res;
}

// ---------------------------------------------------------------------------
extern "C" void kernel_launch(void* const* d_in, const int* in_sizes, int n_in,
                              void* d_out, int out_size, void* d_ws, size_t ws_size,
                              hipStream_t stream) {
    const float* x       = (const float*)d_in[0];
    const float* w       = (const float*)d_in[1];
    const float* h_att   = (const float*)d_in[2];
    const float* h_dec0  = (const float*)d_in[3];
    const float* h_dec1  = (const float*)d_in[4];
    const float* memory  = (const float*)d_in[5];
    const float* pre_w1  = (const float*)d_in[6];
    const float* pre_b1  = (const float*)d_in[7];
    const float* pre_w2  = (const float*)d_in[8];
    const float* pre_b2  = (const float*)d_in[9];
    const float* att_wi  = (const float*)d_in[10];
    const float* att_wh  = (const float*)d_in[11];
    const float* att_bi  = (const float*)d_in[12];
    const float* att_bh  = (const float*)d_in[13];
    const float* q_w     = (const float*)d_in[14];
    const float* q_b     = (const float*)d_in[15];
    const float* dec0_wi = (const float*)d_in[16];
    const float* dec0_wh = (const float*)d_in[17];
    const float* dec0_bi = (const float*)d_in[18];
    const float* dec0_bh = (const float*)d_in[19];
    const float* dec1_wi = (const float*)d_in[20];
    const float* dec1_wh = (const float*)d_in[21];
    const float* dec1_bi = (const float*)d_in[22];
    const float* dec1_bh = (const float*)d_in[23];

    float* out = (float*)d_out;
    float* o_h1a = out;                    // h1        (256*768)
    float* o_wn  = out + 196608;           // w_new     (256*512)
    float* o_ha  = out + 327680;           // h_att_new (256*256)
    float* o_h0  = out + 393216;           // h0        (256*768)
    float* o_h1b = out + 589824;           // h1 again  (256*768)

    float* ws    = (float*)d_ws;
    float* h_pre = ws;                     // 32768
    float* q     = ws + 32768;             // 131072
    float* e     = ws + 163840;            // 131072
    float* x_dec = ws + 294912;            // 196608
    float* gi    = ws + 491520;            // 589824
    float* gh    = ws + 1081344;           // 589824
    float* ctxp  = ws + 1671168;           // 1048576   (8 slices x B x 512)

    prenet_kernel<<<B, 128, 0, stream>>>(x, pre_w1, pre_b1, pre_w2, pre_b2, h_pre);
    attgru_kernel<<<B / 4, 256, 0, stream>>>(h_pre, h_att, att_wi, att_wh, att_bi, att_bh, o_ha, x_dec);
    qproj_kernel<<<B / 4, 512, 0, stream>>>(o_ha, q_w, q_b, q);
    mempass_kernel<<<dim3(8, B), 256, 0, stream>>>(memory, w, q, e, ctxp);
    ctx_reduce_kernel<<<512, 256, 0, stream>>>(ctxp, x_dec);
    softmax_prior_kernel<<<B, 256, 0, stream>>>(e, w, o_wn);

    gemm_bias_kernel<<<dim3(G3 / BN, B / BM, 2), 256, 0, stream>>>(
        x_dec, h_dec0, dec0_wi, dec0_wh, dec0_bi, dec0_bh, gi, gh);
    gru_res_kernel<<<768, 256, 0, stream>>>(x_dec, h_dec0, gi, gh, o_h0, nullptr);

    gemm_bias_kernel<<<dim3(G3 / BN, B / BM, 2), 256, 0, stream>>>(
        o_h0, h_dec1, dec1_wi, dec1_wh, dec1_bi, dec1_bh, gi, gh);
    gru_res_kernel<<<768, 256, 0, stream>>>(o_h0, h_dec1, gi, gh, o_h1a, o_h1b);
}